// Round 7
// baseline (152.194 us; speedup 1.0000x reference)
//
#include <hip/hip_runtime.h>
#include <hip/hip_bf16.h>

#define NNODES 50000
#define DIM    128
#define KNBR   16
#define NPAIRS 100000
#define PBLK   1250    // pair-loss grid: 1250 blocks x 16 pairs x 5 iters = 100000
#define PITER  5

typedef float          f32x4  __attribute__((ext_vector_type(4)));
typedef float          f32x2  __attribute__((ext_vector_type(2)));
typedef __bf16         bf16x8 __attribute__((ext_vector_type(8)));
typedef unsigned short u16x8  __attribute__((ext_vector_type(8)));
typedef unsigned int   u32x2  __attribute__((ext_vector_type(2)));

// ---- bf16 helper (RNE round) ----
__device__ __forceinline__ unsigned short f2bf(float f) {
    unsigned int u = __builtin_bit_cast(unsigned int, f);
    u = (u + 0x7fffu + ((u >> 16) & 1u)) >> 16;
    return (unsigned short)u;
}

// ---- fp8 e4m3 codecs (HW cvt; selector must be literal -> template) ----
#if __has_builtin(__builtin_amdgcn_cvt_pk_f32_fp8) && __has_builtin(__builtin_amdgcn_cvt_pk_fp8_f32)
template <bool HI>
__device__ __forceinline__ f32x2 fp8x2_dec(unsigned int w) {
    return __builtin_amdgcn_cvt_pk_f32_fp8((int)w, HI);
}
template <bool HI>
__device__ __forceinline__ unsigned int fp8x2_enc(float a, float b, unsigned int old) {
    return (unsigned int)__builtin_amdgcn_cvt_pk_fp8_f32(a, b, (int)old, HI);
}
#else
__device__ __forceinline__ float e4m3_dec1(unsigned int b) {
    unsigned int s = (b & 0x80u) << 24;
    unsigned int em = b & 0x7fu;
    float mag = (em >= 8u)
        ? __builtin_bit_cast(float, (((em >> 3) + 120u) << 23) | ((em & 7u) << 20))
        : (float)em * 0.001953125f;
    return __builtin_bit_cast(float, __builtin_bit_cast(unsigned int, mag) | s);
}
template <bool HI>
__device__ __forceinline__ f32x2 fp8x2_dec(unsigned int w) {
    unsigned int v = HI ? (w >> 16) : w;
    f32x2 r; r[0] = e4m3_dec1(v & 0xffu); r[1] = e4m3_dec1((v >> 8) & 0xffu);
    return r;
}
__device__ __forceinline__ unsigned int e4m3_enc1(float f) {
    unsigned int s = (__builtin_bit_cast(unsigned int, f) >> 24) & 0x80u;
    float af = fminf(fabsf(f), 448.0f);
    unsigned int u = __builtin_bit_cast(unsigned int, af);
    int e = (int)(u >> 23) - 127;
    if (e < -9) return s;
    if (e < -6) { int q = (int)rintf(af * 512.0f); return s | (unsigned int)q; }
    unsigned int mant = u & 0x7fffffu;
    unsigned int r = (mant + 0x7ffffu + ((mant >> 20) & 1u)) >> 20;
    unsigned int out = (((unsigned int)(e + 7)) << 3) + r;
    if (out > 0x7eu) out = 0x7eu;
    return s | out;
}
template <bool HI>
__device__ __forceinline__ unsigned int fp8x2_enc(float a, float b, unsigned int old) {
    unsigned int p = e4m3_enc1(a) | (e4m3_enc1(b) << 8);
    return HI ? ((old & 0x0000ffffu) | (p << 16)) : ((old & 0xffff0000u) | p);
}
#endif

#define AS1 __attribute__((address_space(1)))
#define AS3 __attribute__((address_space(3)))
__device__ __forceinline__ void gload_lds16(const void* g, void* l) {
    __builtin_amdgcn_global_load_lds((AS1 void*)(g), (AS3 void*)(l), 16, 0, 0);
}

// ---------------- K0: W1 [256][128] f32 -> W1t [128][256] bf16; zero out -----
__global__ void w1t_kernel(const float* __restrict__ W1, unsigned short* __restrict__ W1t,
                           float* __restrict__ out) {
    int g = blockIdx.x * 256 + threadIdx.x;
    int i = g >> 7;
    int d = g & 127;
    W1t[d * 256 + i] = f2bf(W1[g]);
    if (g == 0) out[0] = 0.f;
}

// ---------------- K1: E f32 -> E8 fp8 (sequential, 8 elems/thread) -----------
__global__ void e2f8_kernel(const float* __restrict__ E, unsigned int* __restrict__ E8) {
    int g = blockIdx.x * 256 + threadIdx.x;
    const f32x4 v0 = *(const f32x4*)(E + (size_t)g * 8);
    const f32x4 v1 = *(const f32x4*)(E + (size_t)g * 8 + 4);
    unsigned int w0 = 0, w1 = 0;
    w0 = fp8x2_enc<false>(v0[0], v0[1], w0);
    w0 = fp8x2_enc<true >(v0[2], v0[3], w0);
    w1 = fp8x2_enc<false>(v1[0], v1[1], w1);
    w1 = fp8x2_enc<true >(v1[2], v1[3], w1);
    u32x2 o; o[0] = w0; o[1] = w1;
    *(u32x2*)(E8 + (size_t)g * 2) = o;
}

// ---------------- agg: dense wave-gather into wave-private LDS ---------------
__device__ __forceinline__ void agg_core(const unsigned char* __restrict__ T,
                                         const int* __restrict__ nbr,
                                         unsigned char* lds_wave,  // 8 KB
                                         int node_base, int lane, float* a) {
    const int rsub = lane >> 3;
    const int bcol = (lane & 7) * 16;
    const int* nb = nbr + node_base * KNBR;
#pragma unroll
    for (int i = 0; i < 8; ++i) {
        int nl = nb[i * 8 + rsub];
        gload_lds16(T + (size_t)nl * 128 + bcol, lds_wave + i * 1024);
    }
    asm volatile("s_waitcnt vmcnt(0)" ::: "memory");
    __builtin_amdgcn_sched_barrier(0);
    const int g = lane >> 4;
    const int c = lane & 15;
#pragma unroll
    for (int j = 0; j < 8; ++j) a[j] = 0.f;
#pragma unroll
    for (int k = 0; k < KNBR; ++k) {
        const u32x2 v = *(const u32x2*)(lds_wave + (g * 16 + k) * 128 + c * 8);
        f32x2 f;
        f = fp8x2_dec<false>(v[0]); a[0] += f[0]; a[1] += f[1];
        f = fp8x2_dec<true >(v[0]); a[2] += f[0]; a[3] += f[1];
        f = fp8x2_dec<false>(v[1]); a[4] += f[0]; a[5] += f[1];
        f = fp8x2_dec<true >(v[1]); a[6] += f[0]; a[7] += f[1];
    }
}

// K2: H1 = mean_k E8[nbr] ; fp8 -> fp8
__global__ __launch_bounds__(256) void agg1_kernel(const unsigned char* __restrict__ E8,
                                                   const int* __restrict__ nbr,
                                                   unsigned char* __restrict__ H1f8) {
    __shared__ unsigned char SL[4][8192];
    const int t = threadIdx.x, wave = t >> 6, lane = t & 63;
    const int node_base = blockIdx.x * 16 + wave * 4;
    float a[8];
    agg_core(E8, nbr, SL[wave], node_base, lane, a);
    const int g = lane >> 4, c = lane & 15;
    unsigned int o0 = 0, o1 = 0;
    o0 = fp8x2_enc<false>(a[0] * 0.0625f, a[1] * 0.0625f, o0);
    o0 = fp8x2_enc<true >(a[2] * 0.0625f, a[3] * 0.0625f, o0);
    o1 = fp8x2_enc<false>(a[4] * 0.0625f, a[5] * 0.0625f, o1);
    o1 = fp8x2_enc<true >(a[6] * 0.0625f, a[7] * 0.0625f, o1);
    u32x2 o; o[0] = o0; o[1] = o1;
    *(u32x2*)(H1f8 + (size_t)(node_base + g) * 128 + c * 8) = o;
}

// K3: H2 = mean_k H1f8[nbr] ; fp8 -> bf16
__global__ __launch_bounds__(256) void agg2_kernel(const unsigned char* __restrict__ H1f8,
                                                   const int* __restrict__ nbr,
                                                   unsigned short* __restrict__ H2b) {
    __shared__ unsigned char SL[4][8192];
    const int t = threadIdx.x, wave = t >> 6, lane = t & 63;
    const int node_base = blockIdx.x * 16 + wave * 4;
    float a[8];
    agg_core(H1f8, nbr, SL[wave], node_base, lane, a);
    const int g = lane >> 4, c = lane & 15;
    u16x8 o;
#pragma unroll
    for (int j = 0; j < 8; ++j) o[j] = f2bf(a[j] * 0.0625f);
    *(u16x8*)(H2b + (size_t)(node_base + g) * DIM + c * 8) = o;
}

// ---------------- K4: PQ = H2 @ [W1_top | W1_bot]  (dense GEMM) --------------
// PQ[n][j] : j<128 -> P[n][j] = sum_k H2[n][k]*W1[k][j]
//            j>=128 -> Q[n][j-128] = sum_k H2[n][k]*W1[128+k][j-128]
// BM=64 rows/block, N=256, K=128. Wave w owns cols [w*64, w*64+64).
__global__ __launch_bounds__(256, 2) void gemmpq_kernel(
    const unsigned short* __restrict__ H2b, const unsigned short* __restrict__ W1t,
    unsigned short* __restrict__ PQb) {
    __shared__ unsigned char  Ast[64 * 256];    // 16 KB swizzled A tile
    __shared__ unsigned short Cbuf[64 * 256];   // 32 KB output staging

    const int tid = threadIdx.x, wave = tid >> 6, lane = tid & 63;
    const int lg = lane >> 4, ll = lane & 15;
    const int rowbase = blockIdx.x * 64;

    // ---- stage A: 4 instrs/wave, 4 rows (256B each) per instr ----
    {
        const int lq = (lane & 15) * 16;
        const int lr = lane >> 4;
#pragma unroll
        for (int i = 0; i < 4; ++i) {
            int r0 = wave * 16 + i * 4;
            int row = r0 + lr;
            int grow = rowbase + row; if (grow >= NNODES) grow = NNODES - 1;
            int b = lq ^ ((row & 7) << 4);   // pre-swizzled source byte
            gload_lds16((const char*)H2b + (size_t)grow * 256 + b, Ast + r0 * 256);
        }
    }

    // ---- B fragments from W1t (L2-hot): [cg][ks] ----
    const int qoff = (wave >= 2) ? 256 : 0;   // waves 0,1: P-half; 2,3: Q-half
    bf16x8 breg[4][4];
#pragma unroll
    for (int cg = 0; cg < 4; ++cg) {
        int jj = (wave * 64 + cg * 16 + ll) & 127;
#pragma unroll
        for (int ks = 0; ks < 4; ++ks)
            breg[cg][ks] = *(const bf16x8*)((const char*)W1t + jj * 512 + qoff + ks * 64 + lg * 16);
    }
    __syncthreads();

    // ---- MFMA: 4 ks x 4 mf x 4 cg ----
    f32x4 acc[4][4];
    {
        f32x4 z = {0.f, 0.f, 0.f, 0.f};
#pragma unroll
        for (int i = 0; i < 4; ++i)
#pragma unroll
            for (int j = 0; j < 4; ++j) acc[i][j] = z;
    }
#pragma unroll
    for (int ks = 0; ks < 4; ++ks) {
#pragma unroll
        for (int mf = 0; mf < 4; ++mf) {
            int row = mf * 16 + ll;
            bf16x8 af = *(const bf16x8*)(Ast + row * 256 + ((ks * 64 + lg * 16) ^ ((row & 7) << 4)));
#pragma unroll
            for (int cg = 0; cg < 4; ++cg)
                acc[mf][cg] = __builtin_amdgcn_mfma_f32_16x16x32_bf16(af, breg[cg][ks], acc[mf][cg], 0, 0, 0);
        }
    }

    // ---- C -> Cbuf (bf16, row-major), then coalesced stream-out ----
#pragma unroll
    for (int mf = 0; mf < 4; ++mf)
#pragma unroll
        for (int cg = 0; cg < 4; ++cg) {
            int col = wave * 64 + cg * 16 + ll;
#pragma unroll
            for (int r = 0; r < 4; ++r)
                Cbuf[(mf * 16 + lg * 4 + r) * 256 + col] = f2bf(acc[mf][cg][r]);
        }
    __syncthreads();
#pragma unroll
    for (int it = 0; it < 8; ++it) {
        int c = tid + it * 256;           // 16B chunk id, 2048 total
        int row = c >> 5, cw = c & 31;
        int grow = rowbase + row;
        if (grow < NNODES)
            *(u16x8*)((char*)PQb + (size_t)grow * 512 + cw * 16) =
                *(const u16x8*)((const char*)Cbuf + row * 512 + cw * 16);
    }
}

// ---------------- K5: streaming pair loss ------------------------------------
// 16 lanes per pair: lane c owns hidden cols [c*8, c*8+8).
// h = relu(P[s] + Q[d] + b1); logits = h@W2 + b2; double-softmax CE.
__global__ __launch_bounds__(256) void pair_loss_kernel(
    const int* __restrict__ pairs, const int* __restrict__ labels,
    const unsigned short* __restrict__ PQb, const float* __restrict__ b1,
    const float* __restrict__ W2, const float* __restrict__ b2,
    float* __restrict__ out) {
    __shared__ float sred[4];
    const int tid = threadIdx.x, wave = tid >> 6, lane = tid & 63;
    const int pg = lane >> 4, c = lane & 15;

    float b1c[8], w2a[8], w2b[8];
#pragma unroll
    for (int j = 0; j < 8; ++j) {
        b1c[j] = b1[c * 8 + j];
        w2a[j] = W2[(c * 8 + j) * 2];
        w2b[j] = W2[(c * 8 + j) * 2 + 1];
    }
    const float b20 = b2[0], b21 = b2[1];

    float lacc = 0.f;
#pragma unroll
    for (int it = 0; it < PITER; ++it) {
        int p = (blockIdx.x + it * PBLK) * 16 + wave * 4 + pg;   // always < NPAIRS
        int s = pairs[p * 2], d = pairs[p * 2 + 1];
        bf16x8 pb = *(const bf16x8*)((const char*)PQb + (size_t)s * 512 + c * 16);
        bf16x8 qb = *(const bf16x8*)((const char*)PQb + (size_t)d * 512 + 256 + c * 16);
        float l0 = 0.f, l1 = 0.f;
#pragma unroll
        for (int j = 0; j < 8; ++j) {
            float h = fmaxf((float)pb[j] + (float)qb[j] + b1c[j], 0.f);
            l0 += h * w2a[j];
            l1 += h * w2b[j];
        }
#pragma unroll
        for (int sdist = 1; sdist < 16; sdist <<= 1) {
            l0 += __shfl_xor(l0, sdist, 16);
            l1 += __shfl_xor(l1, sdist, 16);
        }
        if (c == 0) {
            l0 += b20; l1 += b21;
            float mx = fmaxf(l0, l1);
            float e0 = __expf(l0 - mx), e1 = __expf(l1 - mx);
            float inv = 1.f / (e0 + e1);
            float q0 = e0 * inv, q1 = e1 * inv;
            float lse2 = __logf(__expf(q0) + __expf(q1));
            lacc += lse2 - (labels[p] ? q1 : q0);
        }
    }
#pragma unroll
    for (int sdist = 1; sdist < 64; sdist <<= 1) lacc += __shfl_xor(lacc, sdist, 64);
    if (lane == 0) sred[wave] = lacc;
    __syncthreads();
    if (tid == 0)
        atomicAdd(out, (sred[0] + sred[1] + sred[2] + sred[3]) * (1.0f / (float)NPAIRS));
}

extern "C" void kernel_launch(void* const* d_in, const int* in_sizes, int n_in,
                              void* d_out, int out_size, void* d_ws, size_t ws_size,
                              hipStream_t stream) {
    const int*   pairs  = (const int*)d_in[0];
    const int*   labels = (const int*)d_in[1];
    const int*   nbr    = (const int*)d_in[2];
    const float* E      = (const float*)d_in[3];
    const float* W1     = (const float*)d_in[4];
    const float* b1     = (const float*)d_in[5];
    const float* W2     = (const float*)d_in[6];
    const float* b2     = (const float*)d_in[7];
    float* out = (float*)d_out;

    // workspace (38.5 MB): W1t | H2b | [E8 | H1f8] overlaid later by PQb
    char* ws = (char*)d_ws;
    unsigned short* W1t  = (unsigned short*)(ws);                       // 64 KB
    unsigned short* H2b  = (unsigned short*)(ws + 65536);               // 12.8 MB
    unsigned char*  E8   = (unsigned char*)(ws + 65536 + 12800000);     // 6.4 MB
    unsigned char*  H1f8 = E8 + 6400000;                                // 6.4 MB
    unsigned short* PQb  = (unsigned short*)E8;   // 25.6 MB, overlays E8+H1f8 (dead)

    w1t_kernel<<<dim3(128), dim3(256), 0, stream>>>(W1, W1t, out);
    e2f8_kernel<<<dim3((NNODES * DIM) / (256 * 8)), dim3(256), 0, stream>>>(E, (unsigned int*)E8);
    agg1_kernel<<<dim3(NNODES / 16), dim3(256), 0, stream>>>(E8, nbr, H1f8);
    agg2_kernel<<<dim3(NNODES / 16), dim3(256), 0, stream>>>(H1f8, nbr, H2b);
    gemmpq_kernel<<<dim3((NNODES + 63) / 64), dim3(256), 0, stream>>>(H2b, W1t, PQb);
    pair_loss_kernel<<<dim3(PBLK), dim3(256), 0, stream>>>(pairs, labels, PQb, b1, W2, b2, out);
}